// Round 8
// baseline (7250.966 us; speedup 1.0000x reference)
//
#include <hip/hip_runtime.h>
#include <math.h>

#define T_LEN 4096
#define EDIM  256
#define HDIM  512
#define NTAGS 50
#define SENTW 0xFFFFFFFFu

__device__ __forceinline__ float sigm(float x) {
    return __builtin_amdgcn_rcpf(1.0f + __expf(-x));
}
__device__ __forceinline__ float tanh_fast(float x) {
    float e = __expf(2.0f * x);                       // x>>0 -> inf -> rcp=0 -> 1; x<<0 -> 0 -> -1
    return 1.0f - 2.0f * __builtin_amdgcn_rcpf(e + 1.0f);
}
__device__ __forceinline__ float u2f(unsigned u) { union { unsigned i; float f; } v; v.i = u; return v.f; }
__device__ __forceinline__ float rdlane(float v, int l) {
    union { float f; int i; } a, r;
    a.f = v;
    r.i = __builtin_amdgcn_readlane(a.i, l);   // SGPR broadcast, VALU-only
    return r.f;
}
// Agent-scope relaxed RMW poll: serviced at the device coherence point.
// Laws from rounds 0-7: only coherence-point ops observe cross-CU progress;
// FETCH_SIZE counts L2 fills from the fabric (L3-hit or HBM alike), so poll
// traffic always shows as FETCH; same-line poll pipelining MSHR-merges (r3);
// tight per-lane spin beats ballot/chunk restructures (r6); cache-placement
// tricks (sc0/L2/ring) never reduce the poll RT (r1/r2/r5/r7).
__device__ __forceinline__ unsigned long long pollA(unsigned long long* p) {
    return __hip_atomic_fetch_or(p, 0ull, __ATOMIC_RELAXED, __HIP_MEMORY_SCOPE_AGENT);
}
__device__ __forceinline__ bool bad2(unsigned long long v) {
    return ((unsigned)v == SENTW) || ((unsigned)(v >> 32) == SENTW);
}

// ---------------------------------------------------------------------------
// Persistent bidirectional LSTM scan (f32), data-as-flag sync, SGPR-broadcast
// matvec. Round-8 = round-4 (proven 5.94 ms) with ONLY the epilogue changed:
//   (i)  WAVE-PARALLEL FINALIZE: wave wv finalizes units g*16+wv*4+{0..3}.
//        Post-barrier tail drops from ~300cy serial-on-wave0 (waves 1-3
//        idle) to ~120cy parallel; the h publish - which gates EVERY
//        consumer's discovery, every step, via the producer convoy - happens
//        ~250cy earlier.
//   (ii) EARLY POLL ISSUE: step s+1's first poll is issued right after the
//        barrier, BEFORE the finalize, so its L3 sample lands just after the
//        publish instead of a full finalize later.
//   (iii) pl stride 71 (r1's finalize-read was an 8-way LDS conflict; this
//        layout is ~2-way = free per m136).
// Everything else byte-equivalent to r4: 64 WGs round-robin, pure agent
// sync, tight single-outstanding spin, 4 FMA chains, fast activations,
// atomicExch publish, hs-direct mailbox (0xFF sentinel).
// WG g owns hidden units [g*16,+16) => 64 gate rows. lane = row:
//   q = lane>>4 (gate i,f,g,o), u = lane&15, R = q*512 + g*16 + u.
// Wave wv owns cols [wv*128,+128) of W_hh, [wv*64,+64) of W_ih; lane l polls
// the 8B word covering h cols {wv*128+2l, +1}.
// ---------------------------------------------------------------------------
__global__ __launch_bounds__(256, 1) void lstm_scan(
    const int* __restrict__ sent, const float* __restrict__ emb,
    const float* __restrict__ Wih_f, const float* __restrict__ Whh_f,
    const float* __restrict__ bih_f, const float* __restrict__ bhh_f,
    const float* __restrict__ Wih_b, const float* __restrict__ Whh_b,
    const float* __restrict__ bih_b, const float* __restrict__ bhh_b,
    float* hsf, float* hsb)
{
    const int tid  = threadIdx.x;
    const int lane = tid & 63;
    const int wv   = tid >> 6;          // wave id = column block
    const int dir  = blockIdx.x >> 5;
    const int g    = blockIdx.x & 31;

    const float* Wih = dir ? Wih_b : Wih_f;
    const float* Whh = dir ? Whh_b : Whh_f;
    const float* bih = dir ? bih_b : bih_f;
    const float* bhh = dir ? bhh_b : bhh_f;
    float* hs = dir ? hsb : hsf;

    const int q = lane >> 4;
    const int u = lane & 15;
    const int R = q * 512 + g * 16 + u;

    // W_hh cols [wv*128,+128) of row R -> 128 VGPRs.
    float wh[128];
    {
        const float* base = Whh + (size_t)R * HDIM + wv * 128;
        #pragma unroll
        for (int i = 0; i < 32; ++i) {
            float4 v = *(const float4*)(base + 4 * i);
            wh[4*i] = v.x; wh[4*i+1] = v.y; wh[4*i+2] = v.z; wh[4*i+3] = v.w;
        }
    }
    // W_ih cols [wv*64,+64) of row R -> 64 VGPRs.
    float wx[64];
    {
        const float* base = Wih + (size_t)R * EDIM + wv * 64;
        #pragma unroll
        for (int i = 0; i < 16; ++i) {
            float4 v = *(const float4*)(base + 4 * i);
            wx[4*i] = v.x; wx[4*i+1] = v.y; wx[4*i+2] = v.z; wx[4*i+3] = v.w;
        }
    }
    // Per-wave finalize biases: lanes 0..3 own unit uu = g*16 + wv*4 + lane.
    float bi = 0.f, bff = 0.f, bgg = 0.f, boo = 0.f;
    if (lane < 4) {
        int uu = g * 16 + wv * 4 + lane;
        bi  = bih[uu]        + bhh[uu];
        bff = bih[512 + uu]  + bhh[512 + uu];
        bgg = bih[1024 + uu] + bhh[1024 + uu];
        boo = bih[1536 + uu] + bhh[1536 + uu];
    }

    __shared__ float pl[2][284];        // wave segment stride 71 (~2-way read)
    float c_state = 0.0f;               // valid on lanes 0..3 of each wave

    // Embedding value pipeline: lane holds emb[sent[t]][wv*64 + lane].
    float ecur;
    {
        int t0 = dir ? (T_LEN - 1) : 0;
        ecur = emb[(size_t)sent[t0] * EDIM + wv * 64 + lane];
    }

    unsigned long long* p = nullptr;    // poll for CURRENT step, issued at the
    unsigned long long  v = 0;          // end of the PREVIOUS step (early).

    for (int s = 0; s < T_LEN; ++s) {
        const int t = dir ? (T_LEN - 1 - s) : s;

        // Prefetch next step's embedding value (h-independent).
        float enext = 0.0f;
        if (s + 1 < T_LEN) {
            int tn = dir ? (t - 1) : (t + 1);
            enext = emb[(size_t)sent[tn] * EDIM + wv * 64 + lane];
        }

        // x partial: 64 SGPR-broadcast MACs over 4 independent accumulators
        // (hidden under the in-flight early poll).
        float a0 = 0.f, a1 = 0.f, a2 = 0.f, a3 = 0.f;
        #pragma unroll
        for (int i = 0; i < 16; ++i) {
            a0 = fmaf(wx[4*i+0], rdlane(ecur, 4*i+0), a0);
            a1 = fmaf(wx[4*i+1], rdlane(ecur, 4*i+1), a1);
            a2 = fmaf(wx[4*i+2], rdlane(ecur, 4*i+2), a2);
            a3 = fmaf(wx[4*i+3], rdlane(ecur, 4*i+3), a3);
        }

        if (s > 0) {
            // Tight single-outstanding spin (r4-proven).
            while (bad2(v)) v = pollA(p);
            float h0 = u2f((unsigned)v);
            float h1 = u2f((unsigned)(v >> 32));
            // h partial: 128 SGPR-broadcast MACs, 4 chains.
            #pragma unroll
            for (int i = 0; i < 32; ++i) {
                a0 = fmaf(wh[4*i+0], rdlane(h0, 2*i+0), a0);
                a1 = fmaf(wh[4*i+1], rdlane(h1, 2*i+0), a1);
                a2 = fmaf(wh[4*i+2], rdlane(h0, 2*i+1), a2);
                a3 = fmaf(wh[4*i+3], rdlane(h1, 2*i+1), a3);
            }
        }

        pl[s & 1][wv * 71 + lane] = (a0 + a1) + (a2 + a3);
        __syncthreads();

        // EARLY issue of next step's first poll (before the finalize tail).
        if (s + 1 < T_LEN) {
            p = (unsigned long long*)(hs + (size_t)t * HDIM + wv * 128) + lane;
            v = pollA(p);
        }

        // Wave-parallel finalize: wave wv owns units g*16 + wv*4 + {0..3}.
        // Lane = sw*16 + qq*4 + m reads wave sw's partial of row (qq, m).
        {
            const int sw = lane >> 4;
            const int qq = (lane >> 2) & 3;
            const int m  = lane & 3;
            float val = pl[s & 1][sw * 71 + qq * 16 + wv * 4 + m];
            val += __shfl_xor(val, 16, 64);       // reduce over source waves
            val += __shfl_xor(val, 32, 64);
            const int m2 = lane & 3;
            float gi = __shfl(val, m2,      64);
            float gf = __shfl(val, 4 + m2,  64);
            float gg = __shfl(val, 8 + m2,  64);
            float go = __shfl(val, 12 + m2, 64);
            if (lane < 4) {
                float iv = sigm(gi + bi), fv = sigm(gf + bff);
                float gv = tanh_fast(gg + bgg), ov = sigm(go + boo);
                c_state = fv * c_state + iv * gv;
                float h = ov * tanh_fast(c_state);
                __hip_atomic_exchange(hs + (size_t)t * HDIM + g * 16 + wv * 4 + lane, h,
                                      __ATOMIC_RELAXED, __HIP_MEMORY_SCOPE_AGENT);
            }
        }
        ecur = enext;
    }
}

// ---------------------------------------------------------------------------
// tag_space[t] = [hs_f[t] | hs_b[t]] @ W_out^T + b_out  (f32 out)
// ---------------------------------------------------------------------------
__global__ __launch_bounds__(256) void out_gemm(
    const float* __restrict__ hsf, const float* __restrict__ hsb,
    const float* __restrict__ Wout, const float* __restrict__ bout,
    float* __restrict__ out)
{
    const int t   = blockIdx.x;
    const int tid = threadIdx.x;
    __shared__ float h2[1024];

    if (tid < 128)
        *(float4*)(h2 + tid * 4) = *(const float4*)(hsf + (size_t)t * HDIM + tid * 4);
    else
        *(float4*)(h2 + 512 + (tid - 128) * 4) = *(const float4*)(hsb + (size_t)t * HDIM + (tid - 128) * 4);
    __syncthreads();

    const int wv = tid >> 6, lane = tid & 63;
    for (int tag = wv; tag < NTAGS; tag += 4) {
        const float4* wr = (const float4*)(Wout + (size_t)tag * (2 * HDIM));
        float p = 0.0f;
        #pragma unroll
        for (int c = lane; c < 256; c += 64) {
            float4 wv4 = wr[c];
            float4 hv  = *(const float4*)(h2 + c * 4);
            p += wv4.x * hv.x + wv4.y * hv.y + wv4.z * hv.z + wv4.w * hv.w;
        }
        p += __shfl_down(p, 32, 64);
        p += __shfl_down(p, 16, 64);
        p += __shfl_down(p, 8, 64);
        p += __shfl_down(p, 4, 64);
        p += __shfl_down(p, 2, 64);
        p += __shfl_down(p, 1, 64);
        if (lane == 0) out[(size_t)t * NTAGS + tag] = p + bout[tag];
    }
}

// ---------------------------------------------------------------------------
extern "C" void kernel_launch(void* const* d_in, const int* in_sizes, int n_in,
                              void* d_out, int out_size, void* d_ws, size_t ws_size,
                              hipStream_t stream)
{
    const int*   sent  = (const int*)d_in[0];
    const float* emb   = (const float*)d_in[1];
    const float* Wih_f = (const float*)d_in[2];
    const float* Whh_f = (const float*)d_in[3];
    const float* bih_f = (const float*)d_in[4];
    const float* bhh_f = (const float*)d_in[5];
    const float* Wih_b = (const float*)d_in[6];
    const float* Whh_b = (const float*)d_in[7];
    const float* bih_b = (const float*)d_in[8];
    const float* bhh_b = (const float*)d_in[9];
    const float* Wout  = (const float*)d_in[10];
    const float* bout  = (const float*)d_in[11];
    float* out = (float*)d_out;

    char* ws = (char*)d_ws;
    // Workspace: hsf [4096*512 f32] @ 0 (8 MiB), hsb @ 8 MiB. Both double as
    // sync flags: sentinel-fill with 0xFF (-NaN, never produced by o*tanh(c)).
    float* hsf = (float*)(ws);
    float* hsb = (float*)(ws + 8388608);
    hipMemsetAsync(ws, 0xFF, 16777216, stream);

    lstm_scan<<<64, 256, 0, stream>>>(sent, emb,
                                      Wih_f, Whh_f, bih_f, bhh_f,
                                      Wih_b, Whh_b, bih_b, bhh_b,
                                      hsf, hsb);
    out_gemm<<<T_LEN, 256, 0, stream>>>(hsf, hsb, Wout, bout, out);
}